// Round 3
// baseline (140.725 us; speedup 1.0000x reference)
//
#include <hip/hip_runtime.h>

// Affine-IFS scan: B points, T steps, N=16 affine maps.
// Block = 64 points x 16 waves(=chunks of 32 steps). One kernel:
//  phase0: stage code (int32 0..15) -> LDS bytes, stage transform table
//  phase1: each wave composes its chunk's affine map (M,v) per point (registers)
//  phase2: each wave applies prefix maps [0..wv) to init point (from LDS maps)
//  phase3: each wave replays its chunk, writes (0.5x+0.5, 0.5y+0.5, op) to out

#define B_PTS 16384
#define T_STEPS 512
#define N_TR 16
#define PTS_PER_BLK 64
#define WAVES 16
#define L_CHUNK 32   // T_STEPS / WAVES
#define THREADS 1024

__global__ __launch_bounds__(THREADS, 1)
void ifs_scan_kernel(const float* __restrict__ init_pts,
                     const float* __restrict__ weights,
                     const float* __restrict__ biases,
                     const float* __restrict__ opac,
                     const int*   __restrict__ code,
                     float*       __restrict__ out)
{
    __shared__ unsigned char codeL[T_STEPS][PTS_PER_BLK];   // 32 KB
    __shared__ float maps[WAVES][6][PTS_PER_BLK];           // 24 KB
    __shared__ float tab[7][N_TR];                          // 448 B: w00,w01,w10,w11,bx,by,op

    const int tid  = threadIdx.x;
    const int lane = tid & 63;
    const int wv   = tid >> 6;
    const int base = blockIdx.x * PTS_PER_BLK;

    // ---- phase 0a: stage transform table (transposed, bank-conflict-free) ----
    if (tid < N_TR) {
        const int n = tid;
        tab[0][n] = weights[n * 4 + 0];
        tab[1][n] = weights[n * 4 + 1];
        tab[2][n] = weights[n * 4 + 2];
        tab[3][n] = weights[n * 4 + 3];
        tab[4][n] = biases[n * 2 + 0];
        tab[5][n] = biases[n * 2 + 1];
        tab[6][n] = opac[n];
    }

    // ---- phase 0b: stage code -> LDS bytes. 8192 int4 loads over 1024 thr ----
    // j in [0,8192): t = j>>4, p4 = (j&15)*4. Consecutive lanes -> consecutive
    // 16B global chunks within a t-row (coalesced), consecutive LDS dwords.
    #pragma unroll
    for (int i = 0; i < 8; ++i) {
        const int j  = tid + i * THREADS;
        const int t  = j >> 4;
        const int p4 = (j & 15) << 2;
        const int4 v = *reinterpret_cast<const int4*>(&code[(size_t)t * B_PTS + base + p4]);
        uchar4 pk;
        pk.x = (unsigned char)v.x; pk.y = (unsigned char)v.y;
        pk.z = (unsigned char)v.z; pk.w = (unsigned char)v.w;
        *reinterpret_cast<uchar4*>(&codeL[t][p4]) = pk;
    }
    __syncthreads();

    // ---- phase 1: compose this wave's chunk map (per point = per lane) ----
    float m00 = 1.f, m01 = 0.f, m10 = 0.f, m11 = 1.f, vx = 0.f, vy = 0.f;
    const int t0 = wv * L_CHUNK;
    #pragma unroll 8
    for (int s = 0; s < L_CHUNK; ++s) {
        const int idx = codeL[t0 + s][lane];
        const float a  = tab[0][idx], b  = tab[1][idx];
        const float c  = tab[2][idx], d  = tab[3][idx];
        const float bx = tab[4][idx], by = tab[5][idx];
        const float n00 = a * m00 + b * m10;
        const float n01 = a * m01 + b * m11;
        const float n10 = c * m00 + d * m10;
        const float n11 = c * m01 + d * m11;
        const float nvx = a * vx + b * vy + bx;
        const float nvy = c * vx + d * vy + by;
        m00 = n00; m01 = n01; m10 = n10; m11 = n11; vx = nvx; vy = nvy;
    }
    maps[wv][0][lane] = m00; maps[wv][1][lane] = m01;
    maps[wv][2][lane] = m10; maps[wv][3][lane] = m11;
    maps[wv][4][lane] = vx;  maps[wv][5][lane] = vy;
    __syncthreads();

    // ---- phase 2: apply prefix maps [0..wv) to this point's init ----
    float px = init_pts[(size_t)(base + lane) * 2 + 0];
    float py = init_pts[(size_t)(base + lane) * 2 + 1];
    for (int c = 0; c < wv; ++c) {   // wave-uniform trip count, no divergence
        const float a  = maps[c][0][lane], b = maps[c][1][lane];
        const float cc = maps[c][2][lane], d = maps[c][3][lane];
        const float ex = maps[c][4][lane], ey = maps[c][5][lane];
        const float nx = a * px + b * py + ex;
        const float ny = cc * px + d * py + ey;
        px = nx; py = ny;
    }

    // ---- phase 3: replay chunk, write output (x*0.5+0.5, y*0.5+0.5, op) ----
    float* op = out + (size_t)((size_t)t0 * B_PTS + base + lane) * 3;
    #pragma unroll 8
    for (int s = 0; s < L_CHUNK; ++s) {
        const int idx = codeL[t0 + s][lane];
        const float a  = tab[0][idx], b  = tab[1][idx];
        const float c  = tab[2][idx], d  = tab[3][idx];
        const float bx = tab[4][idx], by = tab[5][idx];
        const float o  = tab[6][idx];
        const float nx = a * px + b * py + bx;
        const float ny = c * px + d * py + by;
        px = nx; py = ny;
        op[0] = px * 0.5f + 0.5f;
        op[1] = py * 0.5f + 0.5f;
        op[2] = o;
        op += (size_t)B_PTS * 3;
    }
}

extern "C" void kernel_launch(void* const* d_in, const int* in_sizes, int n_in,
                              void* d_out, int out_size, void* d_ws, size_t ws_size,
                              hipStream_t stream) {
    const float* init_pts = (const float*)d_in[0];
    const float* weights  = (const float*)d_in[1];
    const float* biases   = (const float*)d_in[2];
    const float* opac     = (const float*)d_in[3];
    const int*   code     = (const int*)d_in[4];
    float*       out      = (float*)d_out;

    ifs_scan_kernel<<<B_PTS / PTS_PER_BLK, THREADS, 0, stream>>>(
        init_pts, weights, biases, opac, code, out);
}

// Round 4
// 140.211 us; speedup vs baseline: 1.0037x; 1.0037x over previous
//
#include <hip/hip_runtime.h>

// Affine-IFS scan: B points, T steps, N=16 affine maps.
// Block = 64 points x 16 waves(=chunks of 32 steps).
//  phase0: stage code -> LDS bytes; stage transforms as float4 pairs
//  phase1: each wave composes its 32-step chunk map (M,v) per point (regs)
//  phase2: each wave applies prefix maps [0..wv) from LDS (float4/float2 packed)
//  phase3: each wave replays its chunk, writes (0.5x+0.5, 0.5y+0.5, op)
// R3->R4: tab packed as 2x float4 (7 scalar LDS reads/step -> 1 byte + 2x b128),
//         maps packed float4+float2 (6 b32 -> b128+b64). Theory: LDS-pipe
//         throughput co-bottleneck (~19us/CU at scalar layout).

#define B_PTS 16384
#define T_STEPS 512
#define N_TR 16
#define PTS_PER_BLK 64
#define WAVES 16
#define L_CHUNK 32   // T_STEPS / WAVES
#define THREADS 1024

__global__ __launch_bounds__(THREADS, 1)
void ifs_scan_kernel(const float* __restrict__ init_pts,
                     const float* __restrict__ weights,
                     const float* __restrict__ biases,
                     const float* __restrict__ opac,
                     const int*   __restrict__ code,
                     float*       __restrict__ out)
{
    __shared__ unsigned char codeL[T_STEPS][PTS_PER_BLK];   // 32 KB
    __shared__ float4 tabA[N_TR];                           // w00,w01,w10,w11
    __shared__ float4 tabB[N_TR];                           // bx,by,op,0
    __shared__ float4 mapsA[WAVES][PTS_PER_BLK];            // 16 KB m00,m01,m10,m11
    __shared__ float2 mapsB[WAVES][PTS_PER_BLK];            // 8 KB  vx,vy
    // total LDS = 32768+256+256+16384+8192 = 57856 B (<64KB static limit)

    const int tid  = threadIdx.x;
    const int lane = tid & 63;
    const int wv   = tid >> 6;
    const int base = blockIdx.x * PTS_PER_BLK;

    // ---- phase 0a: transform tables ----
    if (tid < N_TR) {
        const int n = tid;
        tabA[n] = make_float4(weights[n*4+0], weights[n*4+1],
                              weights[n*4+2], weights[n*4+3]);
        tabB[n] = make_float4(biases[n*2+0], biases[n*2+1], opac[n], 0.f);
    }

    // ---- phase 0b: stage code -> LDS bytes (coalesced int4 global reads) ----
    #pragma unroll
    for (int i = 0; i < 8; ++i) {
        const int j  = tid + i * THREADS;
        const int t  = j >> 4;
        const int p4 = (j & 15) << 2;
        const int4 v = *reinterpret_cast<const int4*>(&code[(size_t)t * B_PTS + base + p4]);
        uchar4 pk;
        pk.x = (unsigned char)v.x; pk.y = (unsigned char)v.y;
        pk.z = (unsigned char)v.z; pk.w = (unsigned char)v.w;
        *reinterpret_cast<uchar4*>(&codeL[t][p4]) = pk;
    }
    __syncthreads();

    // ---- phase 1: compose this wave's chunk map ----
    float m00 = 1.f, m01 = 0.f, m10 = 0.f, m11 = 1.f, vx = 0.f, vy = 0.f;
    const int t0 = wv * L_CHUNK;
    #pragma unroll 8
    for (int s = 0; s < L_CHUNK; ++s) {
        const int idx = codeL[t0 + s][lane];
        const float4 A  = tabA[idx];          // ds_read_b128, <=2-way alias
        const float4 Bv = tabB[idx];
        const float n00 = A.x * m00 + A.y * m10;
        const float n01 = A.x * m01 + A.y * m11;
        const float n10 = A.z * m00 + A.w * m10;
        const float n11 = A.z * m01 + A.w * m11;
        const float nvx = A.x * vx + A.y * vy + Bv.x;
        const float nvy = A.z * vx + A.w * vy + Bv.y;
        m00 = n00; m01 = n01; m10 = n10; m11 = n11; vx = nvx; vy = nvy;
    }
    mapsA[wv][lane] = make_float4(m00, m01, m10, m11);   // b128 contiguous
    mapsB[wv][lane] = make_float2(vx, vy);               // b64 contiguous
    __syncthreads();

    // ---- phase 2: apply prefix maps [0..wv) ----
    float px = init_pts[(size_t)(base + lane) * 2 + 0];
    float py = init_pts[(size_t)(base + lane) * 2 + 1];
    for (int c = 0; c < wv; ++c) {   // wave-uniform trip count
        const float4 M = mapsA[c][lane];
        const float2 V = mapsB[c][lane];
        const float nx = M.x * px + M.y * py + V.x;
        const float ny = M.z * px + M.w * py + V.y;
        px = nx; py = ny;
    }

    // ---- phase 3: replay chunk, write output ----
    float* op = out + (size_t)((size_t)t0 * B_PTS + base + lane) * 3;
    #pragma unroll 8
    for (int s = 0; s < L_CHUNK; ++s) {
        const int idx = codeL[t0 + s][lane];
        const float4 A  = tabA[idx];
        const float4 Bv = tabB[idx];
        const float nx = A.x * px + A.y * py + Bv.x;
        const float ny = A.z * px + A.w * py + Bv.y;
        px = nx; py = ny;
        op[0] = px * 0.5f + 0.5f;
        op[1] = py * 0.5f + 0.5f;
        op[2] = Bv.z;
        op += (size_t)B_PTS * 3;
    }
}

extern "C" void kernel_launch(void* const* d_in, const int* in_sizes, int n_in,
                              void* d_out, int out_size, void* d_ws, size_t ws_size,
                              hipStream_t stream) {
    const float* init_pts = (const float*)d_in[0];
    const float* weights  = (const float*)d_in[1];
    const float* biases   = (const float*)d_in[2];
    const float* opac     = (const float*)d_in[3];
    const int*   code     = (const int*)d_in[4];
    float*       out      = (float*)d_out;

    ifs_scan_kernel<<<B_PTS / PTS_PER_BLK, THREADS, 0, stream>>>(
        init_pts, weights, biases, opac, code, out);
}